// Round 2
// baseline (2274.574 us; speedup 1.0000x reference)
//
#include <hip/hip_runtime.h>
#include <math.h>

// x: [T=12, B=16, N=2048, D=128] fp32; F = 1536; K = 5
#define TT 12
#define BB 16
#define NN 2048
#define DD 128
#define FDIM 1536
#define KTOP 5
#define NCAND 8
#define NROWS (BB * NN)     // 32768
#define NTRI 136            // 16*17/2 upper-tri 128-tiles per batch

typedef __attribute__((ext_vector_type(8))) short short8;   // 8 bf16
typedef __attribute__((ext_vector_type(4))) float f32x4;
typedef const __attribute__((address_space(1))) void* gas_ptr;
typedef __attribute__((address_space(3))) void* las_ptr;

__device__ __forceinline__ unsigned short f2bf(float f) {   // RNE fp32->bf16
    unsigned u = __float_as_uint(f);
    return (unsigned short)((u + 0x7fffu + ((u >> 16) & 1u)) >> 16);
}
__device__ __forceinline__ float bf2f(unsigned short u) {
    return __uint_as_float(((unsigned)u) << 16);
}

// stable top-k (match lax.top_k: desc value, exact ties -> lowest index)
__device__ __forceinline__ bool tk_better(float v1, int i1, float v2, int i2) {
    return (v1 > v2) || (v1 == v2 && i1 < i2);
}
template <int K>
__device__ __forceinline__ void tk_insert(float bv[K], int bi[K], float v, int idx) {
    if (!tk_better(v, idx, bv[K - 1], bi[K - 1])) return;
    bv[K - 1] = v; bi[K - 1] = idx;
#pragma unroll
    for (int k = K - 1; k > 0; --k) {
        if (tk_better(bv[k], bi[k], bv[k - 1], bi[k - 1])) {
            float tv = bv[k]; bv[k] = bv[k - 1]; bv[k - 1] = tv;
            int tx = bi[k]; bi[k] = bi[k - 1]; bi[k - 1] = tx;
        }
    }
}

// ---------------- 1) inverse L2 norm per (b,n): one wave per row (fp32 exact)
__global__ __launch_bounds__(256) void norms_kernel(const float* __restrict__ x,
                                                    float* __restrict__ invn) {
    int lane = threadIdx.x & 63;
    int row  = (blockIdx.x << 2) + (threadIdx.x >> 6);
    int b = row >> 11;
    int n = row & (NN - 1);
    float s = 0.0f;
#pragma unroll
    for (int i = 0; i < 6; ++i) {
        int e = (lane + (i << 6)) << 2;
        int t = e >> 7;
        int d = e & 127;
        const float4 v = *(const float4*)(x + ((((size_t)t * BB + b) * NN + n) << 7) + d);
        s += v.x * v.x + v.y * v.y + v.z * v.z + v.w * v.w;
    }
#pragma unroll
    for (int off = 32; off; off >>= 1) s += __shfl_down(s, off);
    if (lane == 0) invn[row] = 1.0f / sqrtf(s);
}

// ---------------- 2) convert: hi[b][n][t*128+d] = bf16(x * invn[b,n])  (normalized features)
__global__ __launch_bounds__(256) void convert_kernel(const float* __restrict__ x,
                                                      const float* __restrict__ invn,
                                                      unsigned short* __restrict__ hi) {
    int idx = blockIdx.x * 256 + threadIdx.x;     // one float4 of x, linear
    int lin = idx << 2;
    int d = lin & 127;
    int n = (lin >> 7) & (NN - 1);
    int b = (lin >> 18) & 15;
    int t = lin >> 22;
    float s = invn[(b << 11) + n];
    float4 v = *(const float4*)(x + (size_t)lin);
    ushort4 o;
    o.x = f2bf(v.x * s); o.y = f2bf(v.y * s);
    o.z = f2bf(v.z * s); o.w = f2bf(v.w * s);
    *(ushort4*)(hi + (size_t)((b << 11) + n) * FDIM + (t << 7) + d) = o;
}

// ---------------- 3) bf16 MFMA Gram GEMM: 128x128 tri-tile, K=1536, BK=64
// LDS slot swizzle: chunk (m, c) of 8 bf16 stored at slot m*8 + ((c+m)&7).
// Staged via global_load_lds (dest = wave base + lane*16); frag ds_read_b128
// hits all 8 bank-groups across each 8-lane phase (conflict-free).
__global__ __launch_bounds__(256) void gemm_kernel(const unsigned short* __restrict__ hi,
                                                   unsigned short* __restrict__ dist) {
    __shared__ short As[128 * 64];   // 16 KB
    __shared__ short Bs[128 * 64];   // 16 KB

    int t = blockIdx.x % NTRI;
    int b = blockIdx.x / NTRI;
    int i = 0;
    while (i < 15 && ((i + 1) * (33 - (i + 1))) / 2 <= t) ++i;
    int j = i + (t - (i * (33 - i)) / 2);
    int n0 = i << 7, m0 = j << 7;

    int tid = threadIdx.x;
    int w = tid >> 6, l = tid & 63;

    // staging thread->global mapping (inverts the slot swizzle)
    int offG[4], offL[4];
#pragma unroll
    for (int g = 0; g < 4; ++g) {
        int s = g * 256 + tid;
        int m = s >> 3;
        int c = (s - m) & 7;
        offG[g] = m * FDIM + (c << 3);     // element offset
        offL[g] = (g << 12) + (w << 10);   // wave-uniform LDS byte base
    }
    const unsigned short* gA = hi + ((size_t)(b << 11) + n0) * FDIM;
    const unsigned short* gB = hi + ((size_t)(b << 11) + m0) * FDIM;

    // fragment LDS slots (A row = output row, B row = output col; both k-contiguous)
    int aSlot[4][2], bSlot[4][2];
#pragma unroll
    for (int a = 0; a < 4; ++a)
#pragma unroll
        for (int ki = 0; ki < 2; ++ki) {
            int c  = (ki << 2) + (l >> 4);
            int ma = ((w >> 1) << 6) + (a << 4) + (l & 15);
            int mb = ((w & 1) << 6) + (a << 4) + (l & 15);
            aSlot[a][ki] = (ma << 3) + ((c + ma) & 7);
            bSlot[a][ki] = (mb << 3) + ((c + mb) & 7);
        }

    f32x4 acc[4][4];
#pragma unroll
    for (int a = 0; a < 4; ++a)
#pragma unroll
        for (int c = 0; c < 4; ++c) acc[a][c] = (f32x4){0.f, 0.f, 0.f, 0.f};

    for (int kc = 0; kc < 24; ++kc) {
        int ko = kc << 6;
        __syncthreads();                       // all waves done with previous tile
#pragma unroll
        for (int g = 0; g < 4; ++g) {
            __builtin_amdgcn_global_load_lds((gas_ptr)(gA + ko + offG[g]),
                                             (las_ptr)((char*)As + offL[g]), 16, 0, 0);
            __builtin_amdgcn_global_load_lds((gas_ptr)(gB + ko + offG[g]),
                                             (las_ptr)((char*)Bs + offL[g]), 16, 0, 0);
        }
        __syncthreads();                       // vmcnt drained -> staging visible

        short8 af[4][2], bf[4][2];
#pragma unroll
        for (int a = 0; a < 4; ++a)
#pragma unroll
            for (int ki = 0; ki < 2; ++ki) {
                af[a][ki] = *(const short8*)&As[aSlot[a][ki] << 3];
                bf[a][ki] = *(const short8*)&Bs[bSlot[a][ki] << 3];
            }
#pragma unroll
        for (int ki = 0; ki < 2; ++ki)
#pragma unroll
            for (int a = 0; a < 4; ++a)
#pragma unroll
                for (int c = 0; c < 4; ++c)
                    acc[a][c] = __builtin_amdgcn_mfma_f32_16x16x32_bf16(
                        af[a][ki], bf[c][ki], acc[a][c], 0, 0, 0);
    }

    // epilogue: C layout col=lane&15, row=(lane>>4)*4+reg  [m89-verified]
    unsigned short* db = dist + ((size_t)b << 22);
    int rowb = n0 + ((w >> 1) << 6);
    int colb = m0 + ((w & 1) << 6);
#pragma unroll
    for (int a = 0; a < 4; ++a) {
        int r0 = rowb + (a << 4) + ((l >> 4) << 2);
#pragma unroll
        for (int c = 0; c < 4; ++c) {
            int c0 = colb + (c << 4) + (l & 15);
            unsigned short h0 = f2bf(acc[a][c][0]);
            unsigned short h1 = f2bf(acc[a][c][1]);
            unsigned short h2 = f2bf(acc[a][c][2]);
            unsigned short h3 = f2bf(acc[a][c][3]);
            db[(size_t)(r0 + 0) * NN + c0] = h0;
            db[(size_t)(r0 + 1) * NN + c0] = h1;
            db[(size_t)(r0 + 2) * NN + c0] = h2;
            db[(size_t)(r0 + 3) * NN + c0] = h3;
            if (i != j) {
                ushort4 o; o.x = h0; o.y = h1; o.z = h2; o.w = h3;
                *(ushort4*)(db + (size_t)c0 * NN + r0) = o;   // transposed tile, packed
            }
        }
    }
}

// ---------------- 4) approx top-8 candidate indices per row (bf16 dist)
__global__ __launch_bounds__(256) void topk_kernel(const unsigned short* __restrict__ dist,
                                                   int* __restrict__ cand) {
    __shared__ float sv[4][64 * NCAND];
    __shared__ int   si[4][64 * NCAND];
    int wave = threadIdx.x >> 6, lane = threadIdx.x & 63;
    int row  = (blockIdx.x << 2) + wave;
    const unsigned short* p = dist + ((size_t)row << 11);

    float bv[NCAND]; int bi[NCAND];
#pragma unroll
    for (int k = 0; k < NCAND; ++k) { bv[k] = -3.0e38f; bi[k] = 1 << 30; }
    for (int it = 0; it < 4; ++it) {
        int m = ((it << 6) + lane) << 3;
        uint4 u = *(const uint4*)(p + m);
        tk_insert<NCAND>(bv, bi, bf2f((unsigned short)(u.x & 0xffff)), m + 0);
        tk_insert<NCAND>(bv, bi, bf2f((unsigned short)(u.x >> 16)),    m + 1);
        tk_insert<NCAND>(bv, bi, bf2f((unsigned short)(u.y & 0xffff)), m + 2);
        tk_insert<NCAND>(bv, bi, bf2f((unsigned short)(u.y >> 16)),    m + 3);
        tk_insert<NCAND>(bv, bi, bf2f((unsigned short)(u.z & 0xffff)), m + 4);
        tk_insert<NCAND>(bv, bi, bf2f((unsigned short)(u.z >> 16)),    m + 5);
        tk_insert<NCAND>(bv, bi, bf2f((unsigned short)(u.w & 0xffff)), m + 6);
        tk_insert<NCAND>(bv, bi, bf2f((unsigned short)(u.w >> 16)),    m + 7);
    }
#pragma unroll
    for (int k = 0; k < NCAND; ++k) { sv[wave][lane * NCAND + k] = bv[k]; si[wave][lane * NCAND + k] = bi[k]; }
    __syncthreads();
    if ((lane & 7) == 0) {
        float mv[NCAND]; int mi[NCAND];
#pragma unroll
        for (int k = 0; k < NCAND; ++k) { mv[k] = -3.0e38f; mi[k] = 1 << 30; }
        for (int ll = lane; ll < lane + 8; ++ll)
            for (int k = 0; k < NCAND; ++k)
                tk_insert<NCAND>(mv, mi, sv[wave][ll * NCAND + k], si[wave][ll * NCAND + k]);
#pragma unroll
        for (int k = 0; k < NCAND; ++k) { sv[wave][lane * NCAND + k] = mv[k]; si[wave][lane * NCAND + k] = mi[k]; }
    }
    __syncthreads();
    if (lane == 0) {
        float mv[NCAND]; int mi[NCAND];
#pragma unroll
        for (int k = 0; k < NCAND; ++k) { mv[k] = -3.0e38f; mi[k] = 1 << 30; }
        for (int ll = 0; ll < 64; ll += 8)
            for (int k = 0; k < NCAND; ++k)
                tk_insert<NCAND>(mv, mi, sv[wave][ll * NCAND + k], si[wave][ll * NCAND + k]);
#pragma unroll
        for (int k = 0; k < NCAND; ++k) cand[row * NCAND + k] = mi[k];
    }
}

// ---------------- 5) exact fp32 rescore of 8 candidates -> top-5 (one wave per row)
__global__ __launch_bounds__(256) void rescore_kernel(const float* __restrict__ x,
                                                      const float* __restrict__ invn,
                                                      const int* __restrict__ cand,
                                                      float* __restrict__ tv,
                                                      int* __restrict__ ti) {
    int wave = threadIdx.x >> 6, l = threadIdx.x & 63;
    int row  = (blockIdx.x << 2) + wave;
    int b = row >> 11, n = row & (NN - 1);

    float4 fn[6];
#pragma unroll
    for (int p = 0; p < 6; ++p) {
        int e = ((p << 6) + l) << 2;
        int t = e >> 7, d = e & 127;
        fn[p] = *(const float4*)(x + ((((size_t)t * BB + b) * NN + n) << 7) + d);
    }

    float cv[NCAND]; int cix[NCAND];
#pragma unroll
    for (int c = 0; c < NCAND; ++c) {
        int m = cand[row * NCAND + c];
        cix[c] = m;
        float s = 0.0f;
#pragma unroll
        for (int p = 0; p < 6; ++p) {
            int e = ((p << 6) + l) << 2;
            int t = e >> 7, d = e & 127;
            float4 v = *(const float4*)(x + ((((size_t)t * BB + b) * NN + m) << 7) + d);
            s += fn[p].x * v.x + fn[p].y * v.y + fn[p].z * v.z + fn[p].w * v.w;
        }
#pragma unroll
        for (int off = 32; off; off >>= 1) s += __shfl_down(s, off);
        cv[c] = s;   // valid on lane 0
    }
    if (l == 0) {
        float sn = invn[row];
        float bv[KTOP]; int bi[KTOP];
#pragma unroll
        for (int k = 0; k < KTOP; ++k) { bv[k] = -3.0e38f; bi[k] = 1 << 30; }
#pragma unroll
        for (int c = 0; c < NCAND; ++c) {
            float v = cv[c] * sn * invn[(b << 11) + cix[c]];
            tk_insert<KTOP>(bv, bi, v, cix[c]);
        }
#pragma unroll
        for (int k = 0; k < KTOP; ++k) { tv[row * KTOP + k] = bv[k]; ti[row * KTOP + k] = bi[k]; }
    }
}

// ---------------- 6) scatter: out += leaky(v)*0.5 at (n,m) and (m,n)
__global__ __launch_bounds__(256) void scatter_kernel(const float* __restrict__ tv,
                                                      const int* __restrict__ ti,
                                                      float* __restrict__ out) {
    int g = blockIdx.x * 256 + threadIdx.x;
    if (g >= NROWS * KTOP) return;
    int row = g / KTOP;
    int b = row >> 11, n = row & (NN - 1);
    float v = tv[g];
    int m = ti[g];
    float a = (v >= 0.0f ? v : 0.01f * v) * 0.5f;
    float* base = out + ((size_t)b << 22);
    atomicAdd(base + ((size_t)n << 11) + m, a);
    atomicAdd(base + ((size_t)m << 11) + n, a);
}

extern "C" void kernel_launch(void* const* d_in, const int* in_sizes, int n_in,
                              void* d_out, int out_size, void* d_ws, size_t ws_size,
                              hipStream_t stream) {
    const float* x = (const float*)d_in[0];
    float* out = (float*)d_out;

    // d_out doubles as scratch before the final memset:
    //   [0, 134MB)   bf16 dist [16][2048][2048]
    //   [134, 235MB) bf16 normalized features hi [16][2048][1536]
    unsigned short* dist = (unsigned short*)d_out;
    unsigned short* hi   = (unsigned short*)((char*)d_out + 134217728);

    // ws: invn 128KB | cand 1MB | tv 640KB | ti 640KB  (~2.4 MB)
    float* invn = (float*)d_ws;
    int*   cand = (int*)(invn + NROWS);
    float* tv   = (float*)(cand + (size_t)NROWS * NCAND);
    int*   ti   = (int*)(tv + (size_t)NROWS * KTOP);

    norms_kernel<<<NROWS / 4, 256, 0, stream>>>(x, invn);
    convert_kernel<<<(TT * BB * NN * DD / 4) / 256, 256, 0, stream>>>(x, invn, hi);
    gemm_kernel<<<NTRI * BB, 256, 0, stream>>>(hi, dist);
    topk_kernel<<<NROWS / 4, 256, 0, stream>>>(dist, cand);
    rescore_kernel<<<NROWS / 4, 256, 0, stream>>>(x, invn, cand, tv, ti);
    hipMemsetAsync(d_out, 0, (size_t)out_size * sizeof(float), stream);
    scatter_kernel<<<(NROWS * KTOP + 255) / 256, 256, 0, stream>>>(tv, ti, out);
}

// Round 3
// 899.442 us; speedup vs baseline: 2.5289x; 2.5289x over previous
//
#include <hip/hip_runtime.h>
#include <math.h>

// x: [T=12, B=16, N=2048, D=128] fp32; F = 1536; K = 5
#define TT 12
#define BB 16
#define NN 2048
#define DD 128
#define FDIM 1536
#define KTOP 5
#define NCAND 8
#define NROWS (BB * NN)     // 32768
#define NTRI 136            // 16*17/2 upper-tri 128-tiles per batch

typedef __attribute__((ext_vector_type(8))) short short8;   // 8 bf16
typedef __attribute__((ext_vector_type(4))) float f32x4;
typedef const __attribute__((address_space(1))) void* gas_ptr;
typedef __attribute__((address_space(3))) void* las_ptr;

__device__ __forceinline__ unsigned short f2bf(float f) {   // RNE fp32->bf16
    unsigned u = __float_as_uint(f);
    return (unsigned short)((u + 0x7fffu + ((u >> 16) & 1u)) >> 16);
}
// monotone key: order(key) == order(bf16 value); u32-max-compatible
__device__ __forceinline__ unsigned short bf2key(unsigned short h) {
    return (unsigned short)(h ^ (0x8000u | (0xFFFFu * (h >> 15))));
}

// stable top-k (match lax.top_k: desc value, exact ties -> lowest index)
__device__ __forceinline__ bool tk_better(float v1, int i1, float v2, int i2) {
    return (v1 > v2) || (v1 == v2 && i1 < i2);
}
template <int K>
__device__ __forceinline__ void tk_insert(float bv[K], int bi[K], float v, int idx) {
    if (!tk_better(v, idx, bv[K - 1], bi[K - 1])) return;
    bv[K - 1] = v; bi[K - 1] = idx;
#pragma unroll
    for (int k = K - 1; k > 0; --k) {
        if (tk_better(bv[k], bi[k], bv[k - 1], bi[k - 1])) {
            float tv = bv[k]; bv[k] = bv[k - 1]; bv[k - 1] = tv;
            int tx = bi[k]; bi[k] = bi[k - 1]; bi[k - 1] = tx;
        }
    }
}

// ---------------- 1) fused: row norm + normalized bf16 feature conversion (one wave/row)
__global__ __launch_bounds__(256) void normconv_kernel(const float* __restrict__ x,
                                                       float* __restrict__ invn,
                                                       unsigned short* __restrict__ hi) {
    int lane = threadIdx.x & 63;
    int row  = (blockIdx.x << 2) + (threadIdx.x >> 6);
    int b = row >> 11;
    int n = row & (NN - 1);
    float4 f[6];
    float s = 0.0f;
#pragma unroll
    for (int p = 0; p < 6; ++p) {
        int e = ((p << 6) + lane) << 2;          // float index in [0,1536)
        int t = e >> 7, d = e & 127;
        f[p] = *(const float4*)(x + ((((size_t)t * BB + b) * NN + n) << 7) + d);
        s += f[p].x * f[p].x + f[p].y * f[p].y + f[p].z * f[p].z + f[p].w * f[p].w;
    }
#pragma unroll
    for (int off = 1; off < 64; off <<= 1) s += __shfl_xor(s, off);
    float inv = 1.0f / sqrtf(s);
    if (lane == 0) invn[row] = inv;
    unsigned short* hr = hi + (size_t)row * FDIM;
#pragma unroll
    for (int p = 0; p < 6; ++p) {
        int e = ((p << 6) + lane) << 2;
        ushort4 o;
        o.x = f2bf(f[p].x * inv); o.y = f2bf(f[p].y * inv);
        o.z = f2bf(f[p].z * inv); o.w = f2bf(f[p].w * inv);
        *(ushort4*)(hr + e) = o;
    }
}

// ---------------- 2) bf16 MFMA Gram GEMM: 128x128 tri-tile, K=1536, BK=64
// Output: monotone 16-bit KEYS (not bf16) for cheap u32-max top-k downstream.
__global__ __launch_bounds__(256) void gemm_kernel(const unsigned short* __restrict__ hi,
                                                   unsigned short* __restrict__ dist) {
    __shared__ short As[128 * 64];   // 16 KB
    __shared__ short Bs[128 * 64];   // 16 KB

    int t = blockIdx.x % NTRI;
    int b = blockIdx.x / NTRI;
    int i = 0;
    while (i < 15 && ((i + 1) * (33 - (i + 1))) / 2 <= t) ++i;
    int j = i + (t - (i * (33 - i)) / 2);
    int n0 = i << 7, m0 = j << 7;

    int tid = threadIdx.x;
    int w = tid >> 6, l = tid & 63;

    int offG[4], offL[4];
#pragma unroll
    for (int g = 0; g < 4; ++g) {
        int s = g * 256 + tid;
        int m = s >> 3;
        int c = (s - m) & 7;
        offG[g] = m * FDIM + (c << 3);
        offL[g] = (g << 12) + (w << 10);
    }
    const unsigned short* gA = hi + ((size_t)(b << 11) + n0) * FDIM;
    const unsigned short* gB = hi + ((size_t)(b << 11) + m0) * FDIM;

    int aSlot[4][2], bSlot[4][2];
#pragma unroll
    for (int a = 0; a < 4; ++a)
#pragma unroll
        for (int ki = 0; ki < 2; ++ki) {
            int c  = (ki << 2) + (l >> 4);
            int ma = ((w >> 1) << 6) + (a << 4) + (l & 15);
            int mb = ((w & 1) << 6) + (a << 4) + (l & 15);
            aSlot[a][ki] = (ma << 3) + ((c + ma) & 7);
            bSlot[a][ki] = (mb << 3) + ((c + mb) & 7);
        }

    f32x4 acc[4][4];
#pragma unroll
    for (int a = 0; a < 4; ++a)
#pragma unroll
        for (int c = 0; c < 4; ++c) acc[a][c] = (f32x4){0.f, 0.f, 0.f, 0.f};

    for (int kc = 0; kc < 24; ++kc) {
        int ko = kc << 6;
        __syncthreads();
#pragma unroll
        for (int g = 0; g < 4; ++g) {
            __builtin_amdgcn_global_load_lds((gas_ptr)(gA + ko + offG[g]),
                                             (las_ptr)((char*)As + offL[g]), 16, 0, 0);
            __builtin_amdgcn_global_load_lds((gas_ptr)(gB + ko + offG[g]),
                                             (las_ptr)((char*)Bs + offL[g]), 16, 0, 0);
        }
        __syncthreads();

        short8 af[4][2], bf[4][2];
#pragma unroll
        for (int a = 0; a < 4; ++a)
#pragma unroll
            for (int ki = 0; ki < 2; ++ki) {
                af[a][ki] = *(const short8*)&As[aSlot[a][ki] << 3];
                bf[a][ki] = *(const short8*)&Bs[bSlot[a][ki] << 3];
            }
#pragma unroll
        for (int ki = 0; ki < 2; ++ki)
#pragma unroll
            for (int a = 0; a < 4; ++a)
#pragma unroll
                for (int c = 0; c < 4; ++c)
                    acc[a][c] = __builtin_amdgcn_mfma_f32_16x16x32_bf16(
                        af[a][ki], bf[c][ki], acc[a][c], 0, 0, 0);
    }

    // epilogue: C layout col=lane&15, row=(lane>>4)*4+reg  [m89-verified]
    unsigned short* db = dist + ((size_t)b << 22);
    int rowb = n0 + ((w >> 1) << 6);
    int colb = m0 + ((w & 1) << 6);
#pragma unroll
    for (int a = 0; a < 4; ++a) {
        int r0 = rowb + (a << 4) + ((l >> 4) << 2);
#pragma unroll
        for (int c = 0; c < 4; ++c) {
            int c0 = colb + (c << 4) + (l & 15);
            unsigned short h0 = bf2key(f2bf(acc[a][c][0]));
            unsigned short h1 = bf2key(f2bf(acc[a][c][1]));
            unsigned short h2 = bf2key(f2bf(acc[a][c][2]));
            unsigned short h3 = bf2key(f2bf(acc[a][c][3]));
            db[(size_t)(r0 + 0) * NN + c0] = h0;
            db[(size_t)(r0 + 1) * NN + c0] = h1;
            db[(size_t)(r0 + 2) * NN + c0] = h2;
            db[(size_t)(r0 + 3) * NN + c0] = h3;
            if (i != j) {
                ushort4 o; o.x = h0; o.y = h1; o.z = h2; o.w = h3;
                *(ushort4*)(db + (size_t)c0 * NN + r0) = o;
            }
        }
    }
}

// ---------------- 3) top-8 candidates per row via group-max tournament (one wave/row)
// key32 = (monokey16 << 16) | (2047 - idx): u32 max == (value desc, tie -> lowest idx).
// Top-8 elements provably lie within the top-8 of the 256 8-element groups.
__global__ __launch_bounds__(256) void topk_kernel(const unsigned short* __restrict__ dist,
                                                   int* __restrict__ cand) {
    int wave = threadIdx.x >> 6, lane = threadIdx.x & 63;
    int row  = (blockIdx.x << 2) + wave;
    const unsigned short* p = dist + ((size_t)row << 11);

    // phase A: per-lane group maxes (4 groups of 8 consecutive elements)
    unsigned gk[4];
#pragma unroll
    for (int it = 0; it < 4; ++it) {
        int m = (it << 9) + (lane << 3);
        uint4 w2 = *(const uint4*)(p + m);
        unsigned idxv = 2047u - (unsigned)m;
        unsigned best = (w2.x << 16) | idxv;
        unsigned k;
        k = (w2.x & 0xFFFF0000u) | (idxv - 1); best = best > k ? best : k;
        k = (w2.y << 16) | (idxv - 2);         best = best > k ? best : k;
        k = (w2.y & 0xFFFF0000u) | (idxv - 3); best = best > k ? best : k;
        k = (w2.z << 16) | (idxv - 4);         best = best > k ? best : k;
        k = (w2.z & 0xFFFF0000u) | (idxv - 5); best = best > k ? best : k;
        k = (w2.w << 16) | (idxv - 6);         best = best > k ? best : k;
        k = (w2.w & 0xFFFF0000u) | (idxv - 7); best = best > k ? best : k;
        gk[it] = best;
    }

    // phase A': extract top-8 group keys (winner p held by lane p)
    unsigned mywg = 0;
#pragma unroll
    for (int pass = 0; pass < 8; ++pass) {
        unsigned mx0 = gk[0] > gk[1] ? gk[0] : gk[1];
        unsigned mx1 = gk[2] > gk[3] ? gk[2] : gk[3];
        unsigned mx = mx0 > mx1 ? mx0 : mx1;
#pragma unroll
        for (int off = 1; off < 64; off <<= 1) {
            unsigned o = (unsigned)__shfl_xor((int)mx, off);
            mx = mx > o ? mx : o;
        }
        if (lane == pass) mywg = mx;
#pragma unroll
        for (int tt = 0; tt < 4; ++tt)
            if (gk[tt] == mx) gk[tt] = 0;
    }

    // phase B: gather winning groups' 64 elements, extract element-wise top-8
    unsigned gkey = (unsigned)__shfl((int)mywg, lane >> 3);
    int gm = 2047 - (int)(gkey & 0x7FFu);
    int m  = ((gm >> 3) << 3) + (lane & 7);
    unsigned key = ((unsigned)p[m] << 16) | (unsigned)(2047 - m);
    int mycand = 0;
#pragma unroll
    for (int pass = 0; pass < 8; ++pass) {
        unsigned mx = key;
#pragma unroll
        for (int off = 1; off < 64; off <<= 1) {
            unsigned o = (unsigned)__shfl_xor((int)mx, off);
            mx = mx > o ? mx : o;
        }
        if (lane == pass) mycand = 2047 - (int)(mx & 0x7FFu);
        if (key == mx) key = 0;
    }
    if (lane < 8) cand[row * NCAND + lane] = mycand;
}

// ---------------- 4) exact fp32 rescore of 8 candidates -> top-5 (one wave per row)
__global__ __launch_bounds__(256) void rescore_kernel(const float* __restrict__ x,
                                                      const float* __restrict__ invn,
                                                      const int* __restrict__ cand,
                                                      float* __restrict__ tv,
                                                      int* __restrict__ ti) {
    int wave = threadIdx.x >> 6, l = threadIdx.x & 63;
    int row  = (blockIdx.x << 2) + wave;
    int b = row >> 11, n = row & (NN - 1);

    float4 fn[6];
#pragma unroll
    for (int p = 0; p < 6; ++p) {
        int e = ((p << 6) + l) << 2;
        int t = e >> 7, d = e & 127;
        fn[p] = *(const float4*)(x + ((((size_t)t * BB + b) * NN + n) << 7) + d);
    }

    float cv[NCAND]; int cix[NCAND];
#pragma unroll
    for (int c = 0; c < NCAND; ++c) {
        int m = cand[row * NCAND + c];
        cix[c] = m;
        float s = 0.0f;
#pragma unroll
        for (int p = 0; p < 6; ++p) {
            int e = ((p << 6) + l) << 2;
            int t = e >> 7, d = e & 127;
            float4 v = *(const float4*)(x + ((((size_t)t * BB + b) * NN + m) << 7) + d);
            s += fn[p].x * v.x + fn[p].y * v.y + fn[p].z * v.z + fn[p].w * v.w;
        }
#pragma unroll
        for (int off = 32; off; off >>= 1) s += __shfl_down(s, off);
        cv[c] = s;   // valid on lane 0
    }
    if (l == 0) {
        float sn = invn[row];
        float bv[KTOP]; int bi[KTOP];
#pragma unroll
        for (int k = 0; k < KTOP; ++k) { bv[k] = -3.0e38f; bi[k] = 1 << 30; }
#pragma unroll
        for (int c = 0; c < NCAND; ++c) {
            float v = cv[c] * sn * invn[(b << 11) + cix[c]];
            tk_insert<KTOP>(bv, bi, v, cix[c]);
        }
#pragma unroll
        for (int k = 0; k < KTOP; ++k) { tv[row * KTOP + k] = bv[k]; ti[row * KTOP + k] = bi[k]; }
    }
}

// ---------------- 5) scatter: out += leaky(v)*0.5 at (n,m) and (m,n)
__global__ __launch_bounds__(256) void scatter_kernel(const float* __restrict__ tv,
                                                      const int* __restrict__ ti,
                                                      float* __restrict__ out) {
    int g = blockIdx.x * 256 + threadIdx.x;
    if (g >= NROWS * KTOP) return;
    int row = g / KTOP;
    int b = row >> 11, n = row & (NN - 1);
    float v = tv[g];
    int m = ti[g];
    float a = (v >= 0.0f ? v : 0.01f * v) * 0.5f;
    float* base = out + ((size_t)b << 22);
    atomicAdd(base + ((size_t)n << 11) + m, a);
    atomicAdd(base + ((size_t)m << 11) + n, a);
}

extern "C" void kernel_launch(void* const* d_in, const int* in_sizes, int n_in,
                              void* d_out, int out_size, void* d_ws, size_t ws_size,
                              hipStream_t stream) {
    const float* x = (const float*)d_in[0];
    float* out = (float*)d_out;

    // d_out doubles as scratch before the final memset:
    //   [0, 134MB)   16-bit monotone dist keys [16][2048][2048]
    //   [134, 235MB) bf16 normalized features hi [16][2048][1536]
    unsigned short* dist = (unsigned short*)d_out;
    unsigned short* hi   = (unsigned short*)((char*)d_out + 134217728);

    // ws: invn 128KB | cand 1MB | tv 640KB | ti 640KB  (~2.4 MB)
    float* invn = (float*)d_ws;
    int*   cand = (int*)(invn + NROWS);
    float* tv   = (float*)(cand + (size_t)NROWS * NCAND);
    int*   ti   = (int*)(tv + (size_t)NROWS * KTOP);

    normconv_kernel<<<NROWS / 4, 256, 0, stream>>>(x, invn, hi);
    gemm_kernel<<<NTRI * BB, 256, 0, stream>>>(hi, dist);
    topk_kernel<<<NROWS / 4, 256, 0, stream>>>(dist, cand);
    rescore_kernel<<<NROWS / 4, 256, 0, stream>>>(x, invn, cand, tv, ti);
    hipMemsetAsync(d_out, 0, (size_t)out_size * sizeof(float), stream);
    scatter_kernel<<<(NROWS * KTOP + 255) / 256, 256, 0, stream>>>(tv, ti, out);
}